// Round 8
// baseline (940.657 us; speedup 1.0000x reference)
//
#include <hip/hip_runtime.h>
#include <hip/hip_bf16.h>
#include <cstdint>
#include <cstddef>

#define N_TOKENS  4096
#define DIM       2048
#define N_EXPERTS 32
#define TOPK      4
#define INTER     1408
#define TWO_INTER 2816
#define CAP       1024
#define T_ASSIGN  (N_TOKENS*TOPK)

typedef __attribute__((ext_vector_type(8))) short short8;
typedef __attribute__((ext_vector_type(4))) float f32x4;

__device__ __forceinline__ unsigned pack_bf16(float a, float b) {
  unsigned ua = __builtin_bit_cast(unsigned, a);
  unsigned ub = __builtin_bit_cast(unsigned, b);
  ua = (ua + 0x8000u) >> 16;
  ub = (ub + 0x8000u) & 0xFFFF0000u;
  return ua | ub;
}
__device__ __forceinline__ unsigned short bf16_1(float a) {
  return (unsigned short)((__builtin_bit_cast(unsigned, a) + 0x8000u) >> 16);
}

__device__ __forceinline__ void gl_lds16(const void* g, void* l) {
  __builtin_amdgcn_global_load_lds(
      (const __attribute__((address_space(1))) unsigned int*)g,
      (__attribute__((address_space(3))) unsigned int*)l, 16, 0, 0);
}

// ---------------- routing build (+ inverse map pos) ----------------
__global__ void k_build(const int* __restrict__ tmask, const float* __restrict__ w,
                        const int* __restrict__ idx, int* __restrict__ counts,
                        int* __restrict__ tok, float* __restrict__ pb,
                        int* __restrict__ pos) {
  int i = blockIdx.x * 256 + threadIdx.x;
  if (i >= T_ASSIGN) return;
  int t = i >> 2;
  int e = idx[i];
  if (e < 0 || e >= N_EXPERTS) return;
  if (tmask[t] == 0) return;
  int r = atomicAdd(&counts[e], 1);
  if (r < CAP) {
    tok[e * CAP + r] = t;
    pb[e * CAP + r] = w[i];
    pos[i] = e * CAP + r;
  }
}

// ---------------- fp32 -> bf16 linear convert ----------------
__global__ __launch_bounds__(256) void k_conv(const float* __restrict__ src,
                                              __hip_bfloat16* __restrict__ dst, int n4) {
  int i = blockIdx.x * 256 + threadIdx.x;
  int stride = gridDim.x * 256;
  for (; i < n4; i += stride) {
    float4 v = *(const float4*)(src + (size_t)i * 4);
    *(uint2*)(dst + (size_t)i * 4) = make_uint2(pack_bf16(v.x, v.y), pack_bf16(v.z, v.w));
  }
}

// ---------------- fp32 [E][R][C] -> bf16 [E][C][R] transpose-convert ----------------
__global__ __launch_bounds__(256) void k_tconv(const float* __restrict__ src,
                                               __hip_bfloat16* __restrict__ dst,
                                               int R, int C) {
  __shared__ unsigned short s[64][88];
  int nrt = R >> 6, nct = C >> 6;
  int bid = blockIdx.x;
  int e  = bid / (nrt * nct);
  int rr = bid % (nrt * nct);
  int rt = rr / nct, ct = rr % nct;
  int r0 = rt * 64, c0 = ct * 64;
  const float* sp = src + (size_t)e * R * C;
  int t = threadIdx.x;
  int lr  = t >> 4;
  int lc4 = (t & 15) * 4;
  #pragma unroll
  for (int p = 0; p < 4; ++p) {
    int r = lr + p * 16;
    float4 v = *(const float4*)(sp + (size_t)(r0 + r) * C + c0 + lc4);
    s[lc4 + 0][r] = bf16_1(v.x);
    s[lc4 + 1][r] = bf16_1(v.y);
    s[lc4 + 2][r] = bf16_1(v.z);
    s[lc4 + 3][r] = bf16_1(v.w);
  }
  __syncthreads();
  __hip_bfloat16* dp = dst + (size_t)e * C * R;
  int wc   = t >> 2;
  int wr16 = (t & 3) * 16;
  uint4 o0 = *(const uint4*)&s[wc][wr16];
  uint4 o1 = *(const uint4*)&s[wc][wr16 + 8];
  __hip_bfloat16* o = dp + (size_t)(c0 + wc) * R + r0 + wr16;
  *(uint4*)o = o0;
  *(uint4*)(o + 8) = o1;
}

// ---------------- combine: out[t] = sum_k y[pos[t][k]] ----------------
__global__ __launch_bounds__(256) void k_combine(const float* __restrict__ y,
                                                 const int* __restrict__ pos,
                                                 float* __restrict__ out) {
  int gid = blockIdx.x * 256 + threadIdx.x;
  int t  = gid >> 9;
  int d4 = (gid & 511) * 4;
  int4 p = *(const int4*)(pos + t * 4);
  float4 s = make_float4(0.f, 0.f, 0.f, 0.f);
  if (p.x >= 0) { float4 v = *(const float4*)(y + (size_t)p.x * DIM + d4); s.x += v.x; s.y += v.y; s.z += v.z; s.w += v.w; }
  if (p.y >= 0) { float4 v = *(const float4*)(y + (size_t)p.y * DIM + d4); s.x += v.x; s.y += v.y; s.z += v.z; s.w += v.w; }
  if (p.z >= 0) { float4 v = *(const float4*)(y + (size_t)p.z * DIM + d4); s.x += v.x; s.y += v.y; s.z += v.z; s.w += v.w; }
  if (p.w >= 0) { float4 v = *(const float4*)(y + (size_t)p.w * DIM + d4); s.x += v.x; s.y += v.y; s.z += v.z; s.w += v.w; }
  *(float4*)(out + (size_t)t * DIM + d4) = s;
}

// ============ persistent 256x256 grouped GEMMs — 16 waves (4/SIMD) ============
// 1024 threads = 16 waves in a 4M x 4N grid; per-wave output 64x64 (acc 64 VGPR).
// LDS: 2 K-tile buffers x 64KB. Buffer = A tile [256 rows][128B] then B tile same.
// Swizzle: phys 16B-chunk = logical ^ (row&7); inverse applied on GLOBAL source
// column (gl_lds dest stays linear), same XOR on ds_read address.
// Depth-2 pipeline, counted vmcnt(4) (one K-tile = 4 loads/thread in flight).

#define STG(tt) do {                                                   \
    const int k0_ = (tt) * 64;                                         \
    char* d_ = smem + ((tt) & 1) * 65536 + tid * 16;                   \
    gl_lds16(aQ0 + k0_, d_);                                           \
    gl_lds16(aQ1 + k0_, d_ + 16384);                                   \
    gl_lds16(bQ0 + k0_, d_ + 32768);                                   \
    gl_lds16(bQ1 + k0_, d_ + 49152);                                   \
  } while (0)

#define READS(base_, koff_) do {                                       \
    _Pragma("unroll")                                                  \
    for (int mi_ = 0; mi_ < 4; ++mi_)                                  \
      af[mi_] = *(const short8*)((base_) + (wr * 64 + mi_ * 16 + (lane & 15)) * 128 + (koff_)); \
    _Pragma("unroll")                                                  \
    for (int ni_ = 0; ni_ < 4; ++ni_)                                  \
      bf[ni_] = *(const short8*)((base_) + 32768 + (wc * 64 + ni_ * 16 + (lane & 15)) * 128 + (koff_)); \
  } while (0)

#define MFMAS do {                                                     \
    __builtin_amdgcn_s_setprio(1);                                     \
    _Pragma("unroll")                                                  \
    for (int mi_ = 0; mi_ < 4; ++mi_)                                  \
      _Pragma("unroll")                                                \
      for (int ni_ = 0; ni_ < 4; ++ni_)                                \
        acc[mi_][ni_] = __builtin_amdgcn_mfma_f32_16x16x32_bf16(       \
            af[mi_], bf[ni_], acc[mi_][ni_], 0, 0, 0);                 \
    __builtin_amdgcn_s_setprio(0);                                     \
  } while (0)

#define VM4  asm volatile("s_waitcnt vmcnt(4)" ::: "memory")
#define VM0  asm volatile("s_waitcnt vmcnt(0)" ::: "memory")

#define KLOOP(KT) do {                                                 \
    STG(0); STG(1);                                                    \
    VM4;                                                               \
    __builtin_amdgcn_s_barrier();                                      \
    _Pragma("unroll 1")                                                \
    for (int t = 0; t < (KT); ++t) {                                   \
      const char* base = smem + (t & 1) * 65536;                       \
      const int koff0 = (((lane >> 4) << 4)) ^ ((lane & 7) << 4);      \
      READS(base, koff0);                                              \
      MFMAS;                                                           \
      const int koff1 = (64 + ((lane >> 4) << 4)) ^ ((lane & 7) << 4); \
      READS(base, koff1);                                              \
      __builtin_amdgcn_sched_barrier(0);                               \
      __builtin_amdgcn_s_barrier();                                    \
      if (t + 2 < (KT)) STG(t + 2);                                    \
      MFMAS;                                                           \
      if (t < (KT) - 1) {                                              \
        if (t == (KT) - 2) { VM0; } else { VM4; }                      \
        __builtin_amdgcn_s_barrier();                                  \
        __builtin_amdgcn_sched_barrier(0);                             \
      }                                                                \
    }                                                                  \
  } while (0)

// GEMM1 persistent: act = GEGLU( gather(xb) @ gupT[e]^T ) * prob
__global__ __launch_bounds__(1024, 4) void k_gemm1p(
    const __hip_bfloat16* __restrict__ xb, const __hip_bfloat16* __restrict__ gupT,
    const int* __restrict__ counts, const int* __restrict__ tok,
    const float* __restrict__ pb, __hip_bfloat16* __restrict__ act)
{
  __shared__ char smem[131072];
  const int NT = TWO_INTER / 256;  // 11
  const int KT = DIM / 64;         // 32
  const int xcd  = blockIdx.x & 7;
  const int slot = blockIdx.x >> 3;
  const int tid = threadIdx.x, lane = tid & 63, w = tid >> 6;  // 16 waves
  const int wr = w >> 2, wc = w & 3;                            // 4M x 4N
  const int csw = ((tid & 7) ^ ((tid >> 3) & 7)) * 8;           // swizzled src col
  const int r0 = tid >> 3;                                      // staging row 0..127

  int k = 0;
  for (int ei = 0; ei < 4; ++ei) {
    const int e = xcd * 4 + ei;
    int cc = counts[e]; cc = cc > CAP ? CAP : cc;
    const int mtc = (cc + 255) >> 8;
    for (int nt = 0; nt < NT; ++nt)
      for (int mt = 0; mt < mtc; ++mt, ++k) {
        if ((k & 31) != slot) continue;
        const int m0 = mt * 256, n0 = nt * 256;
        __syncthreads();

        const __hip_bfloat16* gT = gupT + (size_t)e * TWO_INTER * DIM;
        const __hip_bfloat16* aQ0 = xb + (size_t)tok[e * CAP + m0 + r0] * DIM + csw;
        const __hip_bfloat16* aQ1 = xb + (size_t)tok[e * CAP + m0 + 128 + r0] * DIM + csw;
        const __hip_bfloat16* bQ0 = gT + (size_t)(n0 + r0) * DIM + csw;
        const __hip_bfloat16* bQ1 = gT + (size_t)(n0 + 128 + r0) * DIM + csw;

        f32x4 acc[4][4];
        #pragma unroll
        for (int i = 0; i < 4; ++i)
          #pragma unroll
          for (int j = 0; j < 4; ++j) acc[i][j] = (f32x4){0.f, 0.f, 0.f, 0.f};
        short8 af[4], bf[4];

        KLOOP(KT);

        // epilogue: GEGLU * prob -> bf16 act
        const int colp = lane & 15;
        const int rgrp = lane >> 4;
        #pragma unroll
        for (int mi = 0; mi < 4; ++mi) {
          #pragma unroll
          for (int j = 0; j < 4; ++j) {
            int rowl = wr * 64 + mi * 16 + rgrp * 4 + j;
            float prob = pb[e * CAP + m0 + rowl];
            size_t arow = (size_t)(e * CAP + m0 + rowl) * INTER;
            #pragma unroll
            for (int ni = 0; ni < 4; ++ni) {
              float v = acc[mi][ni][j];
              float other = __shfl_xor(v, 1, 64);
              if ((lane & 1) == 0) {
                float gate = fminf(v, 7.0f);
                float up   = fminf(fmaxf(other, -7.0f), 7.0f);
                float glu  = gate / (1.0f + __expf(-1.702f * gate));
                float a    = glu * (up + 1.0f) * prob;
                int nh = n0 + wc * 64 + ni * 16 + colp;
                act[arow + (nh >> 1)] = __float2bfloat16(a);
              }
            }
          }
        }
      }
  }
}

// GEMM2 persistent: y = act @ downT[e]^T  (plain stores)
__global__ __launch_bounds__(1024, 4) void k_gemm2p(
    const __hip_bfloat16* __restrict__ act, const __hip_bfloat16* __restrict__ downT,
    const int* __restrict__ counts, float* __restrict__ y)
{
  __shared__ char smem[131072];
  const int NT = DIM / 256;    // 8
  const int KT = INTER / 64;   // 22
  const int xcd  = blockIdx.x & 7;
  const int slot = blockIdx.x >> 3;
  const int tid = threadIdx.x, lane = tid & 63, w = tid >> 6;
  const int wr = w >> 2, wc = w & 3;
  const int csw = ((tid & 7) ^ ((tid >> 3) & 7)) * 8;
  const int r0 = tid >> 3;

  int k = 0;
  for (int ei = 0; ei < 4; ++ei) {
    const int e = xcd * 4 + ei;
    int cc = counts[e]; cc = cc > CAP ? CAP : cc;
    const int mtc = (cc + 255) >> 8;
    for (int nt = 0; nt < NT; ++nt)
      for (int mt = 0; mt < mtc; ++mt, ++k) {
        if ((k & 31) != slot) continue;
        const int m0 = mt * 256, n0 = nt * 256;
        __syncthreads();

        const __hip_bfloat16* dT = downT + (size_t)e * DIM * INTER;
        const __hip_bfloat16* aQ0 = act + (size_t)(e * CAP + m0 + r0) * INTER + csw;
        const __hip_bfloat16* aQ1 = act + (size_t)(e * CAP + m0 + 128 + r0) * INTER + csw;
        const __hip_bfloat16* bQ0 = dT + (size_t)(n0 + r0) * INTER + csw;
        const __hip_bfloat16* bQ1 = dT + (size_t)(n0 + 128 + r0) * INTER + csw;

        f32x4 acc[4][4];
        #pragma unroll
        for (int i = 0; i < 4; ++i)
          #pragma unroll
          for (int j = 0; j < 4; ++j) acc[i][j] = (f32x4){0.f, 0.f, 0.f, 0.f};
        short8 af[4], bf[4];

        KLOOP(KT);

        const int colp = lane & 15;
        const int rgrp = lane >> 4;
        #pragma unroll
        for (int mi = 0; mi < 4; ++mi) {
          #pragma unroll
          for (int j = 0; j < 4; ++j) {
            int rowl = wr * 64 + mi * 16 + rgrp * 4 + j;
            float* yrow = y + (size_t)(e * CAP + m0 + rowl) * DIM + n0;
            #pragma unroll
            for (int ni = 0; ni < 4; ++ni)
              yrow[wc * 64 + ni * 16 + colp] = acc[mi][ni][j];
          }
        }
      }
  }
}

// ================= launch =================

extern "C" void kernel_launch(void* const* d_in, const int* in_sizes, int n_in,
                              void* d_out, int out_size, void* d_ws, size_t ws_size,
                              hipStream_t stream) {
  const float* x     = (const float*)d_in[0];
  const int*   tmask = (const int*)d_in[1];
  const float* w     = (const float*)d_in[2];
  const int*   idx   = (const int*)d_in[3];
  const float* gup   = (const float*)d_in[4];
  const float* down  = (const float*)d_in[5];
  float* out = (float*)d_out;

  char* ws = (char*)d_ws;
  const size_t off_tok   = 256;
  const size_t off_pb    = off_tok + 131072;
  const size_t off_pos   = off_pb + 131072;
  const size_t off_act   = off_pos + 65536;
  const size_t act_bytes = (size_t)N_EXPERTS * CAP * INTER * 2;
  const size_t off_xb    = off_act + act_bytes;
  const size_t xb_bytes  = (size_t)N_TOKENS * DIM * 2;
  const size_t off_gupT  = off_xb + xb_bytes;
  const size_t gupT_b    = (size_t)N_EXPERTS * TWO_INTER * DIM * 2;
  const size_t off_downT = off_gupT + gupT_b;

  int*   counts = (int*)ws;
  int*   tok    = (int*)(ws + off_tok);
  float* pbuf   = (float*)(ws + off_pb);
  int*   pos    = (int*)(ws + off_pos);
  __hip_bfloat16* act   = (__hip_bfloat16*)(ws + off_act);
  __hip_bfloat16* xb    = (__hip_bfloat16*)(ws + off_xb);
  __hip_bfloat16* gupT  = (__hip_bfloat16*)(ws + off_gupT);
  __hip_bfloat16* downT = (__hip_bfloat16*)(ws + off_downT);
  float* y = (float*)(ws + off_gupT);  // reuse gupT region during gemm2/combine

  hipMemsetAsync(ws, 0, off_pos, stream);
  hipMemsetAsync(ws + off_pos, 0xFF, 65536, stream);  // pos = -1
  k_build<<<(T_ASSIGN + 255) / 256, 256, 0, stream>>>(tmask, w, idx, counts, tok, pbuf, pos);

  k_conv<<<2048, 256, 0, stream>>>(x, xb, (N_TOKENS * DIM) / 4);
  k_tconv<<<N_EXPERTS * (DIM / 64) * (TWO_INTER / 64), 256, 0, stream>>>(gup, gupT, DIM, TWO_INTER);
  k_tconv<<<N_EXPERTS * (INTER / 64) * (DIM / 64), 256, 0, stream>>>(down, downT, INTER, DIM);

  k_gemm1p<<<256, 1024, 0, stream>>>(xb, gupT, counts, tok, pbuf, act);
  k_gemm2p<<<256, 1024, 0, stream>>>(act, downT, counts, y);
  k_combine<<<(N_TOKENS * DIM / 4) / 256, 256, 0, stream>>>(y, pos, out);
}

// Round 9
// 878.464 us; speedup vs baseline: 1.0708x; 1.0708x over previous
//
#include <hip/hip_runtime.h>
#include <hip/hip_bf16.h>
#include <cstdint>
#include <cstddef>

#define N_TOKENS  4096
#define DIM       2048
#define N_EXPERTS 32
#define TOPK      4
#define INTER     1408
#define TWO_INTER 2816
#define CAP       1024
#define T_ASSIGN  (N_TOKENS*TOPK)
#define BK        32

typedef __attribute__((ext_vector_type(8))) short short8;
typedef __attribute__((ext_vector_type(4))) float f32x4;

__device__ __forceinline__ unsigned pack_bf16(float a, float b) {
  unsigned ua = __builtin_bit_cast(unsigned, a);
  unsigned ub = __builtin_bit_cast(unsigned, b);
  ua = (ua + 0x8000u) >> 16;
  ub = (ub + 0x8000u) & 0xFFFF0000u;
  return ua | ub;
}
__device__ __forceinline__ unsigned short bf16_1(float a) {
  return (unsigned short)((__builtin_bit_cast(unsigned, a) + 0x8000u) >> 16);
}
__device__ __forceinline__ float bf2f(unsigned u16) {
  return __builtin_bit_cast(float, u16 << 16);
}

__device__ __forceinline__ void gl_lds16(const void* g, void* l) {
  __builtin_amdgcn_global_load_lds(
      (const __attribute__((address_space(1))) unsigned int*)g,
      (__attribute__((address_space(3))) unsigned int*)l, 16, 0, 0);
}

// ---------------- routing build (+ inverse map pos) ----------------
__global__ void k_build(const int* __restrict__ tmask, const float* __restrict__ w,
                        const int* __restrict__ idx, int* __restrict__ counts,
                        int* __restrict__ tok, float* __restrict__ pb,
                        int* __restrict__ pos) {
  int i = blockIdx.x * 256 + threadIdx.x;
  if (i >= T_ASSIGN) return;
  int t = i >> 2;
  int e = idx[i];
  if (e < 0 || e >= N_EXPERTS) return;
  if (tmask[t] == 0) return;
  int r = atomicAdd(&counts[e], 1);
  if (r < CAP) {
    tok[e * CAP + r] = t;
    pb[e * CAP + r] = w[i];
    pos[i] = e * CAP + r;
  }
}

// ---------------- fp32 -> bf16 linear convert ----------------
__global__ __launch_bounds__(256) void k_conv(const float* __restrict__ src,
                                              __hip_bfloat16* __restrict__ dst, int n4) {
  int i = blockIdx.x * 256 + threadIdx.x;
  int stride = gridDim.x * 256;
  for (; i < n4; i += stride) {
    float4 v = *(const float4*)(src + (size_t)i * 4);
    *(uint2*)(dst + (size_t)i * 4) = make_uint2(pack_bf16(v.x, v.y), pack_bf16(v.z, v.w));
  }
}

// ---------------- fp32 [E][R][C] -> bf16 [E][C][R] transpose-convert ----------------
__global__ __launch_bounds__(256) void k_tconv(const float* __restrict__ src,
                                               __hip_bfloat16* __restrict__ dst,
                                               int R, int C) {
  __shared__ unsigned short s[64][88];
  int nrt = R >> 6, nct = C >> 6;
  int bid = blockIdx.x;
  int e  = bid / (nrt * nct);
  int rr = bid % (nrt * nct);
  int rt = rr / nct, ct = rr % nct;
  int r0 = rt * 64, c0 = ct * 64;
  const float* sp = src + (size_t)e * R * C;
  int t = threadIdx.x;
  int lr  = t >> 4;
  int lc4 = (t & 15) * 4;
  #pragma unroll
  for (int p = 0; p < 4; ++p) {
    int r = lr + p * 16;
    float4 v = *(const float4*)(sp + (size_t)(r0 + r) * C + c0 + lc4);
    s[lc4 + 0][r] = bf16_1(v.x);
    s[lc4 + 1][r] = bf16_1(v.y);
    s[lc4 + 2][r] = bf16_1(v.z);
    s[lc4 + 3][r] = bf16_1(v.w);
  }
  __syncthreads();
  __hip_bfloat16* dp = dst + (size_t)e * C * R;
  int wc   = t >> 2;
  int wr16 = (t & 3) * 16;
  uint4 o0 = *(const uint4*)&s[wc][wr16];
  uint4 o1 = *(const uint4*)&s[wc][wr16 + 8];
  __hip_bfloat16* o = dp + (size_t)(c0 + wc) * R + r0 + wr16;
  *(uint4*)o = o0;
  *(uint4*)(o + 8) = o1;
}

// ---------------- combine: out[t] = sum_k y_bf16[pos[t][k]] ----------------
__global__ __launch_bounds__(256) void k_combine(const __hip_bfloat16* __restrict__ y,
                                                 const int* __restrict__ pos,
                                                 float* __restrict__ out) {
  int gid = blockIdx.x * 256 + threadIdx.x;     // 4096 * 256 threads
  int t  = gid >> 8;                            // token
  int c8 = (gid & 255) * 8;                     // 8 bf16 per thread
  int4 p = *(const int4*)(pos + t * 4);
  float s[8] = {0.f, 0.f, 0.f, 0.f, 0.f, 0.f, 0.f, 0.f};
  #pragma unroll
  for (int k = 0; k < 4; ++k) {
    int pp = (k == 0) ? p.x : (k == 1) ? p.y : (k == 2) ? p.z : p.w;
    if (pp >= 0) {
      uint4 v = *(const uint4*)(y + (size_t)pp * DIM + c8);
      s[0] += bf2f(v.x & 0xffffu); s[1] += bf2f(v.x >> 16);
      s[2] += bf2f(v.y & 0xffffu); s[3] += bf2f(v.y >> 16);
      s[4] += bf2f(v.z & 0xffffu); s[5] += bf2f(v.z >> 16);
      s[6] += bf2f(v.w & 0xffffu); s[7] += bf2f(v.w >> 16);
    }
  }
  float* o = out + (size_t)t * DIM + c8;
  *(float4*)o       = make_float4(s[0], s[1], s[2], s[3]);
  *(float4*)(o + 4) = make_float4(s[4], s[5], s[6], s[7]);
}

// ============ persistent M256xN128xBK32 grouped GEMMs — 2 blocks/CU ============
// 512 threads = 8 waves (4M x 2N), per-wave 64x64 output (acc 64 VGPR).
// LDS: dbuf x (A[256 rows][64B] 16KB + B[128 rows][64B] 8KB) = 48KB -> 2 blocks/CU.
// Swizzle: phys 16B-chunk = logical ^ ((row>>1)&3); inverse pre-applied on GLOBAL
// source column (gl_lds dest linear), same XOR on ds_read (rch). Verified 0-conflict.
// Depth-1 pipeline with counted vmcnt(3); cross-block overlap hides the rest.

#define STGX(tt, KT) do {                                              \
    if ((tt) < (KT)) {                                                 \
      const int k0_ = (tt) * BK;                                       \
      char* base_ = smem + ((tt) & 1) * 24576;                         \
      gl_lds16(aR0 + k0_, base_ + w * 2048 + lane * 16);               \
      gl_lds16(aR1 + k0_, base_ + w * 2048 + 1024 + lane * 16);        \
      gl_lds16(bR  + k0_, base_ + 16384 + w * 1024 + lane * 16);       \
    }                                                                  \
  } while (0)

#define KLOOP(KT) do {                                                 \
    STGX(0, KT);                                                       \
    _Pragma("unroll 1")                                                \
    for (int t = 0; t < (KT); ++t) {                                   \
      STGX(t + 1, KT);                                                 \
      if (t + 1 < (KT)) { asm volatile("s_waitcnt vmcnt(3)" ::: "memory"); } \
      else             { asm volatile("s_waitcnt vmcnt(0)" ::: "memory"); } \
      __builtin_amdgcn_s_barrier();                                    \
      const char* Ab_ = smem + (t & 1) * 24576;                        \
      const char* Bb_ = Ab_ + 16384;                                   \
      short8 af_[4], bf_[4];                                           \
      _Pragma("unroll")                                                \
      for (int mi_ = 0; mi_ < 4; ++mi_)                                \
        af_[mi_] = *(const short8*)(Ab_ + (wr * 64 + mi_ * 16 + (lane & 15)) * 64 + rch); \
      _Pragma("unroll")                                                \
      for (int ni_ = 0; ni_ < 4; ++ni_)                                \
        bf_[ni_] = *(const short8*)(Bb_ + (wc * 64 + ni_ * 16 + (lane & 15)) * 64 + rch); \
      __builtin_amdgcn_s_setprio(1);                                   \
      _Pragma("unroll")                                                \
      for (int mi_ = 0; mi_ < 4; ++mi_)                                \
        _Pragma("unroll")                                              \
        for (int ni_ = 0; ni_ < 4; ++ni_)                              \
          acc[mi_][ni_] = __builtin_amdgcn_mfma_f32_16x16x32_bf16(     \
              af_[mi_], bf_[ni_], acc[mi_][ni_], 0, 0, 0);             \
      __builtin_amdgcn_s_setprio(0);                                   \
      __builtin_amdgcn_s_barrier();                                    \
    }                                                                  \
  } while (0)

// GEMM1 persistent: act = GEGLU( gather(xb) @ gupT[e]^T ) * prob
__global__ __launch_bounds__(512, 4) void k_gemm1p(
    const __hip_bfloat16* __restrict__ xb, const __hip_bfloat16* __restrict__ gupT,
    const int* __restrict__ counts, const int* __restrict__ tok,
    const float* __restrict__ pb, __hip_bfloat16* __restrict__ act)
{
  __shared__ char smem[49152];
  const int NT = TWO_INTER / 128;  // 22
  const int KT = DIM / BK;         // 64
  const int xcd  = blockIdx.x & 7;
  const int slot = blockIdx.x >> 3;               // 0..63
  const int tid = threadIdx.x, lane = tid & 63, w = tid >> 6;  // 8 waves
  const int wr = w >> 1, wc = w & 1;                            // 4M x 2N
  const int csw = ((lane & 3) ^ ((lane >> 3) & 3)) * 8;         // swizzled src col
  const int rch = (((lane >> 4) ^ ((lane >> 1) & 3)) << 4);     // swizzled read chunk
  const int rA0 = w * 32 + (lane >> 2);                         // A staging row (j=0)
  const int rB  = w * 16 + (lane >> 2);                         // B staging row

  int k = 0;
  for (int ei = 0; ei < 4; ++ei) {
    const int e = xcd * 4 + ei;
    int cc = counts[e]; cc = cc > CAP ? CAP : cc;
    const int mtc = (cc + 255) >> 8;
    for (int nt = 0; nt < NT; ++nt)
      for (int mt = 0; mt < mtc; ++mt, ++k) {
        if ((k & 63) != slot) continue;
        const int m0 = mt * 256, n0 = nt * 128;
        __syncthreads();

        const __hip_bfloat16* gT = gupT + (size_t)e * TWO_INTER * DIM;
        const __hip_bfloat16* aR0 = xb + (size_t)tok[e * CAP + m0 + rA0] * DIM + csw;
        const __hip_bfloat16* aR1 = xb + (size_t)tok[e * CAP + m0 + rA0 + 16] * DIM + csw;
        const __hip_bfloat16* bR  = gT + (size_t)(n0 + rB) * DIM + csw;

        f32x4 acc[4][4];
        #pragma unroll
        for (int i = 0; i < 4; ++i)
          #pragma unroll
          for (int j = 0; j < 4; ++j) acc[i][j] = (f32x4){0.f, 0.f, 0.f, 0.f};

        KLOOP(KT);

        // epilogue: GEGLU * prob -> bf16 act
        const int colp = lane & 15;
        const int rgrp = lane >> 4;
        #pragma unroll
        for (int mi = 0; mi < 4; ++mi) {
          #pragma unroll
          for (int j = 0; j < 4; ++j) {
            int rowl = wr * 64 + mi * 16 + rgrp * 4 + j;
            float prob = pb[e * CAP + m0 + rowl];
            size_t arow = (size_t)(e * CAP + m0 + rowl) * INTER;
            #pragma unroll
            for (int ni = 0; ni < 4; ++ni) {
              float v = acc[mi][ni][j];
              float other = __shfl_xor(v, 1, 64);
              if ((lane & 1) == 0) {
                float gate = fminf(v, 7.0f);
                float up   = fminf(fmaxf(other, -7.0f), 7.0f);
                float glu  = gate / (1.0f + __expf(-1.702f * gate));
                float a    = glu * (up + 1.0f) * prob;
                int nh = n0 + wc * 64 + ni * 16 + colp;
                act[arow + (nh >> 1)] = __float2bfloat16(a);
              }
            }
          }
        }
      }
  }
}

// GEMM2 persistent: y_bf16 = act @ downT[e]^T  (plain stores)
__global__ __launch_bounds__(512, 4) void k_gemm2p(
    const __hip_bfloat16* __restrict__ act, const __hip_bfloat16* __restrict__ downT,
    const int* __restrict__ counts, __hip_bfloat16* __restrict__ y)
{
  __shared__ char smem[49152];
  const int NT = DIM / 128;    // 16
  const int KT = INTER / BK;   // 44
  const int xcd  = blockIdx.x & 7;
  const int slot = blockIdx.x >> 3;
  const int tid = threadIdx.x, lane = tid & 63, w = tid >> 6;
  const int wr = w >> 1, wc = w & 1;
  const int csw = ((lane & 3) ^ ((lane >> 3) & 3)) * 8;
  const int rch = (((lane >> 4) ^ ((lane >> 1) & 3)) << 4);
  const int rA0 = w * 32 + (lane >> 2);
  const int rB  = w * 16 + (lane >> 2);

  int k = 0;
  for (int ei = 0; ei < 4; ++ei) {
    const int e = xcd * 4 + ei;
    int cc = counts[e]; cc = cc > CAP ? CAP : cc;
    const int mtc = (cc + 255) >> 8;
    for (int nt = 0; nt < NT; ++nt)
      for (int mt = 0; mt < mtc; ++mt, ++k) {
        if ((k & 63) != slot) continue;
        const int m0 = mt * 256, n0 = nt * 128;
        __syncthreads();

        const __hip_bfloat16* dT = downT + (size_t)e * DIM * INTER;
        const __hip_bfloat16* aR0 = act + (size_t)(e * CAP + m0 + rA0) * INTER + csw;
        const __hip_bfloat16* aR1 = act + (size_t)(e * CAP + m0 + rA0 + 16) * INTER + csw;
        const __hip_bfloat16* bR  = dT + (size_t)(n0 + rB) * INTER + csw;

        f32x4 acc[4][4];
        #pragma unroll
        for (int i = 0; i < 4; ++i)
          #pragma unroll
          for (int j = 0; j < 4; ++j) acc[i][j] = (f32x4){0.f, 0.f, 0.f, 0.f};

        KLOOP(KT);

        const int colp = lane & 15;
        const int rgrp = lane >> 4;
        #pragma unroll
        for (int mi = 0; mi < 4; ++mi) {
          #pragma unroll
          for (int j = 0; j < 4; ++j) {
            int rowl = wr * 64 + mi * 16 + rgrp * 4 + j;
            __hip_bfloat16* yrow = y + (size_t)(e * CAP + m0 + rowl) * DIM + n0;
            #pragma unroll
            for (int ni = 0; ni < 4; ++ni)
              yrow[wc * 64 + ni * 16 + colp] = __float2bfloat16(acc[mi][ni][j]);
          }
        }
      }
  }
}

// ================= launch =================

extern "C" void kernel_launch(void* const* d_in, const int* in_sizes, int n_in,
                              void* d_out, int out_size, void* d_ws, size_t ws_size,
                              hipStream_t stream) {
  const float* x     = (const float*)d_in[0];
  const int*   tmask = (const int*)d_in[1];
  const float* w     = (const float*)d_in[2];
  const int*   idx   = (const int*)d_in[3];
  const float* gup   = (const float*)d_in[4];
  const float* down  = (const float*)d_in[5];
  float* out = (float*)d_out;

  char* ws = (char*)d_ws;
  const size_t off_tok   = 256;
  const size_t off_pb    = off_tok + 131072;
  const size_t off_pos   = off_pb + 131072;
  const size_t off_act   = off_pos + 65536;
  const size_t act_bytes = (size_t)N_EXPERTS * CAP * INTER * 2;
  const size_t off_xb    = off_act + act_bytes;
  const size_t xb_bytes  = (size_t)N_TOKENS * DIM * 2;
  const size_t off_gupT  = off_xb + xb_bytes;
  const size_t gupT_b    = (size_t)N_EXPERTS * TWO_INTER * DIM * 2;
  const size_t off_downT = off_gupT + gupT_b;

  int*   counts = (int*)ws;
  int*   tok    = (int*)(ws + off_tok);
  float* pbuf   = (float*)(ws + off_pb);
  int*   pos    = (int*)(ws + off_pos);
  __hip_bfloat16* act   = (__hip_bfloat16*)(ws + off_act);
  __hip_bfloat16* xb    = (__hip_bfloat16*)(ws + off_xb);
  __hip_bfloat16* gupT  = (__hip_bfloat16*)(ws + off_gupT);
  __hip_bfloat16* downT = (__hip_bfloat16*)(ws + off_downT);
  __hip_bfloat16* y     = (__hip_bfloat16*)(ws + off_gupT);  // reuse gupT region (dead after gemm1): 134MB

  hipMemsetAsync(ws, 0, off_pos, stream);
  hipMemsetAsync(ws + off_pos, 0xFF, 65536, stream);  // pos = -1
  k_build<<<(T_ASSIGN + 255) / 256, 256, 0, stream>>>(tmask, w, idx, counts, tok, pbuf, pos);

  k_conv<<<2048, 256, 0, stream>>>(x, xb, (N_TOKENS * DIM) / 4);
  k_tconv<<<N_EXPERTS * (DIM / 64) * (TWO_INTER / 64), 256, 0, stream>>>(gup, gupT, DIM, TWO_INTER);
  k_tconv<<<N_EXPERTS * (INTER / 64) * (DIM / 64), 256, 0, stream>>>(down, downT, INTER, DIM);

  k_gemm1p<<<512, 512, 0, stream>>>(xb, gupT, counts, tok, pbuf, act);
  k_gemm2p<<<512, 512, 0, stream>>>(act, downT, counts, y);
  k_combine<<<N_TOKENS, 256, 0, stream>>>(y, pos, out);
}

// Round 10
// 802.504 us; speedup vs baseline: 1.1722x; 1.0947x over previous
//
#include <hip/hip_runtime.h>
#include <hip/hip_bf16.h>
#include <cstdint>
#include <cstddef>

#define N_TOKENS  4096
#define DIM       2048
#define N_EXPERTS 32
#define TOPK      4
#define INTER     1408
#define TWO_INTER 2816
#define CAP       1024
#define T_ASSIGN  (N_TOKENS*TOPK)
#define BK        32

typedef __attribute__((ext_vector_type(8))) short short8;
typedef __attribute__((ext_vector_type(4))) float f32x4;

__device__ __forceinline__ unsigned pack_bf16(float a, float b) {
  unsigned ua = __builtin_bit_cast(unsigned, a);
  unsigned ub = __builtin_bit_cast(unsigned, b);
  ua = (ua + 0x8000u) >> 16;
  ub = (ub + 0x8000u) & 0xFFFF0000u;
  return ua | ub;
}
__device__ __forceinline__ unsigned short bf16_1(float a) {
  return (unsigned short)((__builtin_bit_cast(unsigned, a) + 0x8000u) >> 16);
}
__device__ __forceinline__ float bf2f(unsigned u16) {
  return __builtin_bit_cast(float, u16 << 16);
}

__device__ __forceinline__ void gl_lds16(const void* g, void* l) {
  __builtin_amdgcn_global_load_lds(
      (const __attribute__((address_space(1))) unsigned int*)g,
      (__attribute__((address_space(3))) unsigned int*)l, 16, 0, 0);
}

// ---------------- routing build (+ inverse map pos) ----------------
__global__ void k_build(const int* __restrict__ tmask, const float* __restrict__ w,
                        const int* __restrict__ idx, int* __restrict__ counts,
                        int* __restrict__ tok, float* __restrict__ pb,
                        int* __restrict__ pos) {
  int i = blockIdx.x * 256 + threadIdx.x;
  if (i >= T_ASSIGN) return;
  int t = i >> 2;
  int e = idx[i];
  if (e < 0 || e >= N_EXPERTS) return;
  if (tmask[t] == 0) return;
  int r = atomicAdd(&counts[e], 1);
  if (r < CAP) {
    tok[e * CAP + r] = t;
    pb[e * CAP + r] = w[i];
    pos[i] = e * CAP + r;
  }
}

// ---------------- fp32 -> bf16 linear convert (x only) ----------------
__global__ __launch_bounds__(256) void k_conv(const float* __restrict__ src,
                                              __hip_bfloat16* __restrict__ dst, int n4) {
  int i = blockIdx.x * 256 + threadIdx.x;
  int stride = gridDim.x * 256;
  for (; i < n4; i += stride) {
    float4 v = *(const float4*)(src + (size_t)i * 4);
    *(uint2*)(dst + (size_t)i * 4) = make_uint2(pack_bf16(v.x, v.y), pack_bf16(v.z, v.w));
  }
}

// ---------------- combine: out[t] = sum_k y_bf16[pos[t][k]] ----------------
__global__ __launch_bounds__(256) void k_combine(const __hip_bfloat16* __restrict__ y,
                                                 const int* __restrict__ pos,
                                                 float* __restrict__ out) {
  int gid = blockIdx.x * 256 + threadIdx.x;
  int t  = gid >> 8;
  int c8 = (gid & 255) * 8;
  int4 p = *(const int4*)(pos + t * 4);
  float s[8] = {0.f, 0.f, 0.f, 0.f, 0.f, 0.f, 0.f, 0.f};
  #pragma unroll
  for (int k = 0; k < 4; ++k) {
    int pp = (k == 0) ? p.x : (k == 1) ? p.y : (k == 2) ? p.z : p.w;
    if (pp >= 0) {
      uint4 v = *(const uint4*)(y + (size_t)pp * DIM + c8);
      s[0] += bf2f(v.x & 0xffffu); s[1] += bf2f(v.x >> 16);
      s[2] += bf2f(v.y & 0xffffu); s[3] += bf2f(v.y >> 16);
      s[4] += bf2f(v.z & 0xffffu); s[5] += bf2f(v.z >> 16);
      s[6] += bf2f(v.w & 0xffffu); s[7] += bf2f(v.w >> 16);
    }
  }
  float* o = out + (size_t)t * DIM + c8;
  *(float4*)o       = make_float4(s[0], s[1], s[2], s[3]);
  *(float4*)(o + 4) = make_float4(s[4], s[5], s[6], s[7]);
}

// ====== persistent M256 x N128 x BK32 grouped GEMMs, fp32-direct B ======
// LDS per buffer (dbuf stride 32768):
//   A: [256 rows][64B bf16] 16KB  — swizzled chunks (phys = logical ^ ((row>>1)&3)),
//      staged via gl_lds with pre-swizzled global column (csw).
//   B: [32 k][128 n] fp32 16KB    — LINEAR; gl_lds dest tid*16 == k*512 + n*4.
// A-frag: ds_read_b128 (rch swizzle). B-frag: 8x ds_read_b32 stride 512B
// (banks = n%32: 16 distinct x 4-way broadcast = conflict-free), cvt to bf16 in reg.
// Depth-1 pipeline, counted vmcnt(4). Per-XCD dynamic atomic work queue.

#define STG(tt, KT) do {                                                     \
    if ((tt) < (KT)) {                                                       \
      char* base_ = smem + ((tt) & 1) * 32768;                               \
      const int ka_ = (tt) * BK;                                             \
      gl_lds16(aR0 + ka_, base_ + w * 2048 + lane * 16);                     \
      gl_lds16(aR1 + ka_, base_ + w * 2048 + 1024 + lane * 16);              \
      const size_t kb_ = (size_t)(tt) * BK * LDB;                            \
      gl_lds16(bR0 + kb_, base_ + 16384 + w * 1024 + lane * 16);             \
      gl_lds16(bR1 + kb_, base_ + 16384 + 8192 + w * 1024 + lane * 16);      \
    }                                                                        \
  } while (0)

#define KLOOP(KT) do {                                                       \
    STG(0, KT);                                                              \
    _Pragma("unroll 1")                                                      \
    for (int t = 0; t < (KT); ++t) {                                         \
      STG(t + 1, KT);                                                        \
      if (t + 1 < (KT)) { asm volatile("s_waitcnt vmcnt(4)" ::: "memory"); } \
      else             { asm volatile("s_waitcnt vmcnt(0)" ::: "memory"); }  \
      __builtin_amdgcn_s_barrier();                                          \
      const char* Ab_ = smem + (t & 1) * 32768;                              \
      const float* bq_ = (const float*)(Ab_ + 16384 + ((lane >> 4) << 3) * 512) \
                         + (wc * 64 + (lane & 15));                          \
      short8 af_[4];                                                         \
      _Pragma("unroll")                                                      \
      for (int mi_ = 0; mi_ < 4; ++mi_)                                      \
        af_[mi_] = *(const short8*)(Ab_ + (wr * 64 + mi_ * 16 + (lane & 15)) * 64 + rch); \
      _Pragma("unroll")                                                      \
      for (int ni_ = 0; ni_ < 4; ++ni_) {                                    \
        const float* q_ = bq_ + ni_ * 16;                                    \
        short8 bf_;                                                          \
        _Pragma("unroll")                                                    \
        for (int j_ = 0; j_ < 8; ++j_)                                       \
          bf_[j_] = (short)bf16_1(q_[j_ * 128]);                             \
        __builtin_amdgcn_s_setprio(1);                                       \
        _Pragma("unroll")                                                    \
        for (int mi_ = 0; mi_ < 4; ++mi_)                                    \
          acc[mi_][ni_] = __builtin_amdgcn_mfma_f32_16x16x32_bf16(           \
              af_[mi_], bf_, acc[mi_][ni_], 0, 0, 0);                        \
        __builtin_amdgcn_s_setprio(0);                                       \
      }                                                                      \
      __builtin_amdgcn_s_barrier();                                          \
    }                                                                        \
  } while (0)

// GEMM1: act = GEGLU( gather(xb) @ gup[e] ) * prob   (gup fp32 native [d][n])
__global__ __launch_bounds__(512, 4) void k_gemm1p(
    const __hip_bfloat16* __restrict__ xb, const float* __restrict__ gup,
    const int* __restrict__ counts, const int* __restrict__ tok,
    const float* __restrict__ pb, __hip_bfloat16* __restrict__ act,
    int* __restrict__ qh)
{
  __shared__ char smem[65536];
  __shared__ int s_item;
  const int NT = TWO_INTER / 128;   // 22
  const int KT = DIM / BK;          // 64
  const size_t LDB = TWO_INTER;
  const int xcd = blockIdx.x & 7;
  const int tid = threadIdx.x, lane = tid & 63, w = tid >> 6;  // 8 waves
  const int wr = w >> 1, wc = w & 1;                            // 4M x 2N
  const int csw = ((lane & 3) ^ ((lane >> 3) & 3)) * 8;         // A src col swizzle
  const int rch = (((lane >> 4) ^ ((lane >> 1) & 3)) << 4);     // A read chunk
  const int rA0 = w * 32 + (lane >> 2);                         // A staging row
  const int bk0 = tid >> 5;                                     // B staging k row
  const int bn4 = (tid & 31) * 4;                               // B staging n col

  // item table for this XCD's 4 experts
  int mtcs[4], pre[5];
  pre[0] = 0;
  #pragma unroll
  for (int ei = 0; ei < 4; ++ei) {
    int cc = counts[xcd * 4 + ei]; cc = cc > CAP ? CAP : cc;
    mtcs[ei] = (cc + 255) >> 8;
    pre[ei + 1] = pre[ei] + NT * mtcs[ei];
  }
  const int total = pre[4];

  for (;;) {
    if (tid == 0) s_item = atomicAdd(&qh[xcd], 1);
    __syncthreads();
    const int it = s_item;
    if (it >= total) break;
    int ei = (it >= pre[1]) + (it >= pre[2]) + (it >= pre[3]);
    int loc = it - pre[ei];
    int mtc = mtcs[ei];
    int nt = loc / mtc, mt = loc - nt * mtc;
    const int e = xcd * 4 + ei;
    const int m0 = mt * 256, n0 = nt * 128;

    const float* gW = gup + (size_t)e * DIM * TWO_INTER + n0;
    const __hip_bfloat16* aR0 = xb + (size_t)tok[e * CAP + m0 + rA0] * DIM + csw;
    const __hip_bfloat16* aR1 = xb + (size_t)tok[e * CAP + m0 + rA0 + 16] * DIM + csw;
    const float* bR0 = gW + (size_t)bk0 * LDB + bn4;
    const float* bR1 = gW + (size_t)(bk0 + 16) * LDB + bn4;

    f32x4 acc[4][4];
    #pragma unroll
    for (int i = 0; i < 4; ++i)
      #pragma unroll
      for (int j = 0; j < 4; ++j) acc[i][j] = (f32x4){0.f, 0.f, 0.f, 0.f};

    KLOOP(KT);

    // epilogue: GEGLU * prob -> bf16 act
    const int colp = lane & 15;
    const int rgrp = lane >> 4;
    #pragma unroll
    for (int mi = 0; mi < 4; ++mi) {
      #pragma unroll
      for (int j = 0; j < 4; ++j) {
        int rowl = wr * 64 + mi * 16 + rgrp * 4 + j;
        float prob = pb[e * CAP + m0 + rowl];
        size_t arow = (size_t)(e * CAP + m0 + rowl) * INTER;
        #pragma unroll
        for (int ni = 0; ni < 4; ++ni) {
          float v = acc[mi][ni][j];
          float other = __shfl_xor(v, 1, 64);
          if ((lane & 1) == 0) {
            float gate = fminf(v, 7.0f);
            float up   = fminf(fmaxf(other, -7.0f), 7.0f);
            float glu  = gate / (1.0f + __expf(-1.702f * gate));
            float a    = glu * (up + 1.0f) * prob;
            int nh = n0 + wc * 64 + ni * 16 + colp;
            act[arow + (nh >> 1)] = __float2bfloat16(a);
          }
        }
      }
    }
    __syncthreads();
  }
}

// GEMM2: y_bf16 = act @ down[e]   (down fp32 native [k][n]); plain stores
__global__ __launch_bounds__(512, 4) void k_gemm2p(
    const __hip_bfloat16* __restrict__ act, const float* __restrict__ down,
    const int* __restrict__ counts, __hip_bfloat16* __restrict__ y,
    int* __restrict__ qh)
{
  __shared__ char smem[65536];
  __shared__ int s_item;
  const int NT = DIM / 128;     // 16
  const int KT = INTER / BK;    // 44
  const size_t LDB = DIM;
  const int xcd = blockIdx.x & 7;
  const int tid = threadIdx.x, lane = tid & 63, w = tid >> 6;
  const int wr = w >> 1, wc = w & 1;
  const int csw = ((lane & 3) ^ ((lane >> 3) & 3)) * 8;
  const int rch = (((lane >> 4) ^ ((lane >> 1) & 3)) << 4);
  const int rA0 = w * 32 + (lane >> 2);
  const int bk0 = tid >> 5;
  const int bn4 = (tid & 31) * 4;

  int mtcs[4], pre[5];
  pre[0] = 0;
  #pragma unroll
  for (int ei = 0; ei < 4; ++ei) {
    int cc = counts[xcd * 4 + ei]; cc = cc > CAP ? CAP : cc;
    mtcs[ei] = (cc + 255) >> 8;
    pre[ei + 1] = pre[ei] + NT * mtcs[ei];
  }
  const int total = pre[4];

  for (;;) {
    if (tid == 0) s_item = atomicAdd(&qh[xcd], 1);
    __syncthreads();
    const int it = s_item;
    if (it >= total) break;
    int ei = (it >= pre[1]) + (it >= pre[2]) + (it >= pre[3]);
    int loc = it - pre[ei];
    int mtc = mtcs[ei];
    int nt = loc / mtc, mt = loc - nt * mtc;
    const int e = xcd * 4 + ei;
    const int m0 = mt * 256, n0 = nt * 128;

    const float* dW = down + (size_t)e * INTER * DIM + n0;
    const __hip_bfloat16* aR0 = act + (size_t)(e * CAP + m0 + rA0) * INTER + csw;
    const __hip_bfloat16* aR1 = act + (size_t)(e * CAP + m0 + rA0 + 16) * INTER + csw;
    const float* bR0 = dW + (size_t)bk0 * LDB + bn4;
    const float* bR1 = dW + (size_t)(bk0 + 16) * LDB + bn4;

    f32x4 acc[4][4];
    #pragma unroll
    for (int i = 0; i < 4; ++i)
      #pragma unroll
      for (int j = 0; j < 4; ++j) acc[i][j] = (f32x4){0.f, 0.f, 0.f, 0.f};

    KLOOP(KT);

    const int colp = lane & 15;
    const int rgrp = lane >> 4;
    #pragma unroll
    for (int mi = 0; mi < 4; ++mi) {
      #pragma unroll
      for (int j = 0; j < 4; ++j) {
        int rowl = wr * 64 + mi * 16 + rgrp * 4 + j;
        __hip_bfloat16* yrow = y + (size_t)(e * CAP + m0 + rowl) * DIM + n0;
        #pragma unroll
        for (int ni = 0; ni < 4; ++ni)
          yrow[wc * 64 + ni * 16 + colp] = __float2bfloat16(acc[mi][ni][j]);
      }
    }
    __syncthreads();
  }
}

// ================= launch =================

extern "C" void kernel_launch(void* const* d_in, const int* in_sizes, int n_in,
                              void* d_out, int out_size, void* d_ws, size_t ws_size,
                              hipStream_t stream) {
  const float* x     = (const float*)d_in[0];
  const int*   tmask = (const int*)d_in[1];
  const float* w     = (const float*)d_in[2];
  const int*   idx   = (const int*)d_in[3];
  const float* gup   = (const float*)d_in[4];
  const float* down  = (const float*)d_in[5];
  float* out = (float*)d_out;

  char* ws = (char*)d_ws;
  const size_t off_qh1   = 128;                      // 8 ints
  const size_t off_qh2   = 160;                      // 8 ints
  const size_t off_tok   = 256;
  const size_t off_pb    = off_tok + 131072;
  const size_t off_pos   = off_pb + 131072;
  const size_t off_act   = off_pos + 65536;
  const size_t act_bytes = (size_t)N_EXPERTS * CAP * INTER * 2;
  const size_t off_xb    = off_act + act_bytes;
  const size_t xb_bytes  = (size_t)N_TOKENS * DIM * 2;
  const size_t off_y     = off_xb + xb_bytes;        // 134 MB bf16

  int*   counts = (int*)ws;
  int*   qh1    = (int*)(ws + off_qh1);
  int*   qh2    = (int*)(ws + off_qh2);
  int*   tok    = (int*)(ws + off_tok);
  float* pbuf   = (float*)(ws + off_pb);
  int*   pos    = (int*)(ws + off_pos);
  __hip_bfloat16* act = (__hip_bfloat16*)(ws + off_act);
  __hip_bfloat16* xb  = (__hip_bfloat16*)(ws + off_xb);
  __hip_bfloat16* y   = (__hip_bfloat16*)(ws + off_y);

  hipMemsetAsync(ws, 0, off_pos, stream);            // counts, queues, tok, pb
  hipMemsetAsync(ws + off_pos, 0xFF, 65536, stream); // pos = -1
  k_build<<<(T_ASSIGN + 255) / 256, 256, 0, stream>>>(tmask, w, idx, counts, tok, pbuf, pos);

  k_conv<<<2048, 256, 0, stream>>>(x, xb, (N_TOKENS * DIM) / 4);

  k_gemm1p<<<512, 512, 0, stream>>>(xb, gup, counts, tok, pbuf, act, qh1);
  k_gemm2p<<<512, 512, 0, stream>>>(act, down, counts, y, qh2);
  k_combine<<<N_TOKENS, 256, 0, stream>>>(y, pos, out);
}